// Round 4
// baseline (120.821 us; speedup 1.0000x reference)
//
#include <hip/hip_runtime.h>
#include <stdint.h>

// FSUMGUCell: hy = (1-fg)*ng + fg*hx
//   fg = ( [hx|x]@w_f^T + b_f + 1 ) * 0.5
//   ng =   [fg*hx|x]@w_n^T + b_n
// B=H=I=2048, K=H+I=4096. bf16 MFMA path.
//
// Round 4: phase-split K-loop (T3) + setprio around MFMA (T5) on the round-3
// split-K structure. Each BK=64 step = 2 phases (one per kk):
//   [ds_read 8xb128 | kk0: STAGE next] [bar] [setprio MFMA x16] [kk1: vmcnt(0)] [bar]
// vmcnt(0) waits loads issued ~2 phases (~1500 cyc) earlier -> no stall.
// EPI1 reads bf16(fg*hx) from A2 instead of re-reading hx (-16 MB HBM).

#define Hdim 2048
#define Idim 2048
#define Bdim 2048
#define Ktot 4096
#define KHALF 2048
#define NSTEP (KHALF / 64)

typedef __bf16 bf16;
typedef __bf16 bf16x8 __attribute__((ext_vector_type(8)));
typedef float  f32x4  __attribute__((ext_vector_type(4)));

__device__ __forceinline__ void gload_lds16(const bf16* g, bf16* l) {
  __builtin_amdgcn_global_load_lds(
      (const __attribute__((address_space(1))) unsigned int*)g,
      (__attribute__((address_space(3))) unsigned int*)l,
      16, 0, 0);
}

// ---- prep: f32 -> bf16 conversion (vectorized x8) ----
__global__ void cvt_kernel(const float* __restrict__ src, bf16* __restrict__ dst, int n8) {
  int stride = gridDim.x * blockDim.x;
  for (int i = blockIdx.x * blockDim.x + threadIdx.x; i < n8; i += stride) {
    const float4* s = (const float4*)src + (size_t)i * 2;
    float4 a = s[0], b = s[1];
    bf16x8 o;
    o[0]=(bf16)a.x; o[1]=(bf16)a.y; o[2]=(bf16)a.z; o[3]=(bf16)a.w;
    o[4]=(bf16)b.x; o[5]=(bf16)b.y; o[6]=(bf16)b.z; o[7]=(bf16)b.w;
    *((bf16x8*)dst + i) = o;
  }
}

// ---- prep: A1 = [hx | x] bf16; A2 right half = x bf16 ----
__global__ void build_a_kernel(const float* __restrict__ hx, const float* __restrict__ x,
                               bf16* __restrict__ A1, bf16* __restrict__ A2) {
  int stride = gridDim.x * blockDim.x;
  const int n8 = Bdim * Ktot / 8;
  for (int i = blockIdx.x * blockDim.x + threadIdx.x; i < n8; i += stride) {
    int e = i * 8;
    int b = e >> 12;            // / 4096
    int k = e & (Ktot - 1);
    const float* src = (k < Hdim) ? (hx + (size_t)b * Hdim + k)
                                  : (x  + (size_t)b * Idim + (k - Hdim));
    const float4* s = (const float4*)src;
    float4 va = s[0], vb = s[1];
    bf16x8 o;
    o[0]=(bf16)va.x; o[1]=(bf16)va.y; o[2]=(bf16)va.z; o[3]=(bf16)va.w;
    o[4]=(bf16)vb.x; o[5]=(bf16)vb.y; o[6]=(bf16)vb.z; o[7]=(bf16)vb.w;
    *((bf16x8*)A1 + i) = o;
    if (k >= Hdim) *((bf16x8*)A2 + i) = o;
  }
}

// ---- 128x128 GEMM, split-K in-block, 8 waves, phase-split + setprio ----
// A [2048][4096] bf16 rm, W [2048][4096] bf16 rm (= B^T layout).
// C[row][col] = sum_k A[row][k] * W[col][k].
// Per group: LDS tiles [128][64] bf16 x2 bufs; 16B-chunk XOR swizzle
// (LDS[row][c] holds global chunk c ^ (row&7); staged via inverse-swizzled
// global source since global_load_lds writes linearly; read applies same XOR).
template<int EPI>
__global__ __launch_bounds__(512)
void gemm_kernel(const bf16* __restrict__ A, const bf16* __restrict__ W,
                 const float* __restrict__ bias,
                 const float* __restrict__ hx,  // EPI0 only
                 float* __restrict__ FG,        // EPI0: write fg ; EPI1: read fg
                 bf16* __restrict__ A2,         // EPI0: write bf16(fg*hx) ; EPI1: read it
                 float* __restrict__ OUT)       // EPI1: write hy
{
  __shared__ bf16 lds[2][2][2][8192];   // [group][buf][A=0/B=1][128*64] = 128 KB

  int bid  = blockIdx.x;
  int sbid = (bid & 7) * 32 + (bid >> 3);   // XCD swizzle (256%8==0, bijective)
  int tm = sbid >> 4, tn = sbid & 15;

  int tid  = threadIdx.x;
  int w = tid >> 6, lane = tid & 63;
  int g = w >> 2, sub = w & 3;
  int wrow = (sub >> 1) * 64;   // 2x2 wave grid within tile: 64x64 per wave
  int wcol = (sub & 1) * 64;
  int fr = lane & 15, fq = lane >> 4;
  int swz = fr & 7;

  // staging: per group-step 2048 16B chunks (A 1024 + B 1024), 256 threads ->
  // 8 loads/thread. Thread gtid, pass j: row = j*32 + (gtid>>3), dest chunk
  // gtid&7, source chunk (gtid&7)^(row&7) (inverse swizzle).
  int gtid = sub * 64 + lane;
  int srow = gtid >> 3;
  int csrc = (gtid & 7) ^ (srow & 7);
  const bf16* pA = A + (size_t)(tm * 128 + srow) * Ktot + csrc * 8 + g * KHALF;
  const bf16* pB = W + (size_t)(tn * 128 + srow) * Ktot + csrc * 8 + g * KHALF;
  int lbase = sub * 512;                     // + j*2048 ; gload adds lane*16B

#define STAGE(buf, koff) do {                                                      \
    _Pragma("unroll")                                                              \
    for (int j = 0; j < 4; ++j) {                                                  \
      gload_lds16(pA + (size_t)j * 32 * Ktot + (koff), &lds[g][buf][0][j * 2048 + lbase]); \
      gload_lds16(pB + (size_t)j * 32 * Ktot + (koff), &lds[g][buf][1][j * 2048 + lbase]); \
    }                                                                              \
  } while (0)

  f32x4 acc[4][4] = {};

  STAGE(0, 0);
  asm volatile("s_waitcnt vmcnt(0)" ::: "memory");
  __builtin_amdgcn_s_barrier();

  int cur = 0;
  for (int t = 0; t < NSTEP; ++t) {
    const bool pf = (t + 1 < NSTEP);
    #pragma unroll
    for (int kk = 0; kk < 2; ++kk) {
      bf16x8 af[4], bv[4];
      int ch = ((kk * 4 + fq) ^ swz) * 8;
      #pragma unroll
      for (int m = 0; m < 4; ++m)
        af[m] = *(const bf16x8*)&lds[g][cur][0][(wrow + m * 16 + fr) * 64 + ch];
      #pragma unroll
      for (int n = 0; n < 4; ++n)
        bv[n] = *(const bf16x8*)&lds[g][cur][1][(wcol + n * 16 + fr) * 64 + ch];
      if (kk == 0 && pf) STAGE(cur ^ 1, (t + 1) * 64);   // prefetch next K-tile
      __builtin_amdgcn_sched_barrier(0);                 // pin reads+stage pre-bar
      __builtin_amdgcn_s_barrier();
      __builtin_amdgcn_s_setprio(1);
      #pragma unroll
      for (int m = 0; m < 4; ++m)
        #pragma unroll
        for (int n = 0; n < 4; ++n)
          acc[m][n] = __builtin_amdgcn_mfma_f32_16x16x32_bf16(af[m], bv[n], acc[m][n], 0, 0, 0);
      __builtin_amdgcn_s_setprio(0);
      if (kk == 1 && pf)                                 // loads ~2 phases old -> no stall
        asm volatile("s_waitcnt vmcnt(0)" ::: "memory");
      __builtin_amdgcn_sched_barrier(0);
      __builtin_amdgcn_s_barrier();
    }
    cur ^= 1;
  }
#undef STAGE

  // ---- cross-group reduction via LDS (reuse tile space), fused epilogue ----
  __syncthreads();
  float* xch = (float*)&lds[0][0][0][0];    // 4 subs x 16 KB = 64 KB
  if (g == 1) {
    #pragma unroll
    for (int m = 0; m < 4; ++m)
      #pragma unroll
      for (int n = 0; n < 4; ++n)
        *(f32x4*)&xch[sub * 4096 + (m * 4 + n) * 256 + lane * 4] = acc[m][n];
  }
  __syncthreads();
  if (g == 0) {
    // C/D layout: col = lane&15, row = (lane>>4)*4 + i  [m89 verified]
    int row0 = tm * 128 + wrow + fq * 4;
    int col0 = tn * 128 + wcol + fr;
    #pragma unroll
    for (int n = 0; n < 4; ++n) {
      int gcol = col0 + n * 16;
      float bv = bias[gcol];
      #pragma unroll
      for (int m = 0; m < 4; ++m) {
        f32x4 part = *(const f32x4*)&xch[sub * 4096 + (m * 4 + n) * 256 + lane * 4];
        #pragma unroll
        for (int i = 0; i < 4; ++i) {
          int grow = row0 + m * 16 + i;
          size_t idx = (size_t)grow * Hdim + gcol;
          float v = acc[m][n][i] + part[i] + bv;
          if (EPI == 0) {
            float fg   = (v + 1.0f) * 0.5f;
            float fghx = fg * hx[idx];
            FG[idx] = fg;                                  // fp32 fg staged in d_out
            A2[(size_t)grow * Ktot + gcol] = (bf16)fghx;   // GEMM2 A-operand, left half
          } else {
            float fg   = FG[idx];                          // read before overwrite
            float fghx = (float)A2[(size_t)grow * Ktot + gcol]; // bf16(fg*hx), reused
            OUT[idx] = v - fg * v + fghx;                  // (1-fg)*ng + fg*hx
          }
        }
      }
    }
  }
}

extern "C" void kernel_launch(void* const* d_in, const int* in_sizes, int n_in,
                              void* d_out, int out_size, void* d_ws, size_t ws_size,
                              hipStream_t stream) {
  const float* x   = (const float*)d_in[0];
  const float* hx  = (const float*)d_in[1];
  const float* w_f = (const float*)d_in[2];
  const float* b_f = (const float*)d_in[3];
  const float* w_n = (const float*)d_in[4];
  const float* b_n = (const float*)d_in[5];
  float* out = (float*)d_out;

  bf16* A1 = (bf16*)d_ws;
  bf16* A2 = A1 + (size_t)Bdim * Ktot;
  bf16* Wf = A2 + (size_t)Bdim * Ktot;
  bf16* Wn = Wf + (size_t)Hdim * Ktot;
  // total ws use: 4 * 16.78 MB = 67.1 MB

  const int n8w = Hdim * Ktot / 8;
  cvt_kernel<<<1024, 256, 0, stream>>>(w_f, Wf, n8w);
  cvt_kernel<<<1024, 256, 0, stream>>>(w_n, Wn, n8w);
  build_a_kernel<<<1024, 256, 0, stream>>>(hx, x, A1, A2);

  // GEMM1: fg path. fg (fp32) staged in d_out; bf16(fg*hx) -> A2 left half.
  gemm_kernel<0><<<256, 512, 0, stream>>>(A1, Wf, b_f, hx, out, A2, nullptr);
  // GEMM2: ng path + final hy into d_out (reads fg from d_out, fg*hx from A2).
  gemm_kernel<1><<<256, 512, 0, stream>>>(A2, Wn, b_n, nullptr, out, A2, out);
}

// Round 6
// 117.870 us; speedup vs baseline: 1.0250x; 1.0250x over previous
//
#include <hip/hip_runtime.h>
#include <stdint.h>

// FSUMGUCell: hy = (1-fg)*ng + fg*hx
//   fg = ( [hx|x]@w_f^T + b_f + 1 ) * 0.5
//   ng =   [fg*hx|x]@w_n^T + b_n
// B=H=I=2048, K=H+I=4096. bf16 MFMA path.
//
// Round 6: window-staggered split-K, RACE-FIXED. Group 1 trails group 0 by one
// window; 1 barrier per window. j==0 windows: own vmcnt(0) -> BARRIER (all
// group waves' stage loads complete) -> ds_reads + STAGE next -> MFMA.
// j==1 windows: ds_reads pre-barrier (tile proven complete last window) ->
// barrier -> MFMA. Round-5's bug: j==0 reads were pre-barrier, guarded only
// by the wave's OWN vmcnt -> read other waves' un-landed stage data.

#define Hdim 2048
#define Idim 2048
#define Bdim 2048
#define Ktot 4096
#define KHALF 2048
#define NSTEP (KHALF / 64)

typedef __bf16 bf16;
typedef __bf16 bf16x8 __attribute__((ext_vector_type(8)));
typedef float  f32x4  __attribute__((ext_vector_type(4)));

__device__ __forceinline__ void gload_lds16(const bf16* g, bf16* l) {
  __builtin_amdgcn_global_load_lds(
      (const __attribute__((address_space(1))) unsigned int*)g,
      (__attribute__((address_space(3))) unsigned int*)l,
      16, 0, 0);
}

// ---- prep: f32 -> bf16 conversion (vectorized x8) ----
__global__ void cvt_kernel(const float* __restrict__ src, bf16* __restrict__ dst, int n8) {
  int stride = gridDim.x * blockDim.x;
  for (int i = blockIdx.x * blockDim.x + threadIdx.x; i < n8; i += stride) {
    const float4* s = (const float4*)src + (size_t)i * 2;
    float4 a = s[0], b = s[1];
    bf16x8 o;
    o[0]=(bf16)a.x; o[1]=(bf16)a.y; o[2]=(bf16)a.z; o[3]=(bf16)a.w;
    o[4]=(bf16)b.x; o[5]=(bf16)b.y; o[6]=(bf16)b.z; o[7]=(bf16)b.w;
    *((bf16x8*)dst + i) = o;
  }
}

// ---- prep: A1 = [hx | x] bf16; A2 right half = x bf16 ----
__global__ void build_a_kernel(const float* __restrict__ hx, const float* __restrict__ x,
                               bf16* __restrict__ A1, bf16* __restrict__ A2) {
  int stride = gridDim.x * blockDim.x;
  const int n8 = Bdim * Ktot / 8;
  for (int i = blockIdx.x * blockDim.x + threadIdx.x; i < n8; i += stride) {
    int e = i * 8;
    int b = e >> 12;            // / 4096
    int k = e & (Ktot - 1);
    const float* src = (k < Hdim) ? (hx + (size_t)b * Hdim + k)
                                  : (x  + (size_t)b * Idim + (k - Hdim));
    const float4* s = (const float4*)src;
    float4 va = s[0], vb = s[1];
    bf16x8 o;
    o[0]=(bf16)va.x; o[1]=(bf16)va.y; o[2]=(bf16)va.z; o[3]=(bf16)va.w;
    o[4]=(bf16)vb.x; o[5]=(bf16)vb.y; o[6]=(bf16)vb.z; o[7]=(bf16)vb.w;
    *((bf16x8*)A1 + i) = o;
    if (k >= Hdim) *((bf16x8*)A2 + i) = o;
  }
}

// ---- 128x128 GEMM, split-K in-block, 8 waves, staggered windows ----
// A [2048][4096] bf16 rm, W [2048][4096] bf16 rm (= B^T layout).
// C[row][col] = sum_k A[row][k] * W[col][k].
// Per group: LDS tiles [128][64] bf16 x2 bufs; 16B-chunk XOR swizzle
// (LDS[row][c] holds global chunk c ^ (row&7); staged via inverse-swizzled
// global source since global_load_lds writes linearly; read applies same XOR).
template<int EPI>
__global__ __launch_bounds__(512)
void gemm_kernel(const bf16* __restrict__ A, const bf16* __restrict__ W,
                 const float* __restrict__ bias,
                 const float* __restrict__ hx,  // EPI0 only
                 float* __restrict__ FG,        // EPI0: write fg ; EPI1: read fg
                 bf16* __restrict__ A2,         // EPI0: write bf16(fg*hx) ; EPI1: read it
                 float* __restrict__ OUT)       // EPI1: write hy
{
  __shared__ bf16 lds[2][2][2][8192];   // [group][buf][A=0/B=1][128*64] = 128 KB

  int bid  = blockIdx.x;
  int sbid = (bid & 7) * 32 + (bid >> 3);   // XCD swizzle (256%8==0, bijective)
  int tm = sbid >> 4, tn = sbid & 15;

  int tid  = threadIdx.x;
  int w = tid >> 6, lane = tid & 63;
  int g = w >> 2, sub = w & 3;
  int wrow = (sub >> 1) * 64;   // 2x2 wave grid within tile: 64x64 per wave
  int wcol = (sub & 1) * 64;
  int fr = lane & 15, fq = lane >> 4;
  int swz = fr & 7;

  // staging: per group-step 2048 16B chunks (A 1024 + B 1024), 256 threads ->
  // 8 loads/thread. Thread gtid, pass j: row = j*32 + (gtid>>3), dest chunk
  // gtid&7, source chunk (gtid&7)^(row&7) (inverse swizzle).
  int gtid = sub * 64 + lane;
  int srow = gtid >> 3;
  int csrc = (gtid & 7) ^ (srow & 7);
  const bf16* pA = A + (size_t)(tm * 128 + srow) * Ktot + csrc * 8 + g * KHALF;
  const bf16* pB = W + (size_t)(tn * 128 + srow) * Ktot + csrc * 8 + g * KHALF;
  int lbase = sub * 512;                     // + j*2048 ; gload adds lane*16B

#define STAGE(buf, koff) do {                                                      \
    _Pragma("unroll")                                                              \
    for (int jj = 0; jj < 4; ++jj) {                                               \
      gload_lds16(pA + (size_t)jj * 32 * Ktot + (koff), &lds[g][buf][0][jj * 2048 + lbase]); \
      gload_lds16(pB + (size_t)jj * 32 * Ktot + (koff), &lds[g][buf][1][jj * 2048 + lbase]); \
    }                                                                              \
  } while (0)

#define READS(buf_, j_) do {                                                       \
    int ch = (((j_) * 4 + fq) ^ swz) * 8;                                          \
    _Pragma("unroll")                                                              \
    for (int m = 0; m < 4; ++m)                                                    \
      af[m] = *(const bf16x8*)&lds[g][buf_][0][(wrow + m * 16 + fr) * 64 + ch];    \
    _Pragma("unroll")                                                              \
    for (int n = 0; n < 4; ++n)                                                    \
      bv[n] = *(const bf16x8*)&lds[g][buf_][1][(wcol + n * 16 + fr) * 64 + ch];    \
  } while (0)

  f32x4 acc[4][4] = {};

  STAGE(0, 0);                          // prologue: tile 0 -> buf 0

  const int NW = 2 * NSTEP + 1;         // 65 windows; g1 trails by 1
  for (int win = 0; win < NW; ++win) {
    int w2 = win - g;
    bool active = (unsigned)w2 < (unsigned)(2 * NSTEP);
    int t = w2 >> 1, j = w2 & 1, buf = t & 1;
    bf16x8 af[4], bv[4];
    if (active) {
      if (j == 1) READS(buf, 1);        // tile complete since last window: safe
      else asm volatile("s_waitcnt vmcnt(0)" ::: "memory");  // own stage loads done
    }
    __builtin_amdgcn_s_barrier();       // group-wide: stage(t) fully landed
    if (active) {
      if (j == 0) {
        READS(buf, 0);                  // AFTER barrier (round-5 race fix)
        if (t + 1 < NSTEP) STAGE(buf ^ 1, (t + 1) * 64);
      }
      __builtin_amdgcn_s_setprio(1);
      #pragma unroll
      for (int m = 0; m < 4; ++m)
        #pragma unroll
        for (int n = 0; n < 4; ++n)
          acc[m][n] = __builtin_amdgcn_mfma_f32_16x16x32_bf16(af[m], bv[n], acc[m][n], 0, 0, 0);
      __builtin_amdgcn_s_setprio(0);
    }
  }
#undef STAGE
#undef READS

  // ---- cross-group reduction via LDS (reuse tile space), fused epilogue ----
  __syncthreads();
  float* xch = (float*)&lds[0][0][0][0];    // 4 subs x 16 KB = 64 KB
  if (g == 1) {
    #pragma unroll
    for (int m = 0; m < 4; ++m)
      #pragma unroll
      for (int n = 0; n < 4; ++n)
        *(f32x4*)&xch[sub * 4096 + (m * 4 + n) * 256 + lane * 4] = acc[m][n];
  }
  __syncthreads();
  if (g == 0) {
    // C/D layout: col = lane&15, row = (lane>>4)*4 + i  [m89 verified]
    int row0 = tm * 128 + wrow + fq * 4;
    int col0 = tn * 128 + wcol + fr;
    #pragma unroll
    for (int n = 0; n < 4; ++n) {
      int gcol = col0 + n * 16;
      float bv = bias[gcol];
      #pragma unroll
      for (int m = 0; m < 4; ++m) {
        f32x4 part = *(const f32x4*)&xch[sub * 4096 + (m * 4 + n) * 256 + lane * 4];
        #pragma unroll
        for (int i = 0; i < 4; ++i) {
          int grow = row0 + m * 16 + i;
          size_t idx = (size_t)grow * Hdim + gcol;
          float v = acc[m][n][i] + part[i] + bv;
          if (EPI == 0) {
            float fg   = (v + 1.0f) * 0.5f;
            float fghx = fg * hx[idx];
            FG[idx] = fg;                                  // fp32 fg staged in d_out
            A2[(size_t)grow * Ktot + gcol] = (bf16)fghx;   // GEMM2 A-operand, left half
          } else {
            float fg   = FG[idx];                          // read before overwrite
            float fghx = (float)A2[(size_t)grow * Ktot + gcol]; // bf16(fg*hx), reused
            OUT[idx] = v - fg * v + fghx;                  // (1-fg)*ng + fg*hx
          }
        }
      }
    }
  }
}

extern "C" void kernel_launch(void* const* d_in, const int* in_sizes, int n_in,
                              void* d_out, int out_size, void* d_ws, size_t ws_size,
                              hipStream_t stream) {
  const float* x   = (const float*)d_in[0];
  const float* hx  = (const float*)d_in[1];
  const float* w_f = (const float*)d_in[2];
  const float* b_f = (const float*)d_in[3];
  const float* w_n = (const float*)d_in[4];
  const float* b_n = (const float*)d_in[5];
  float* out = (float*)d_out;

  bf16* A1 = (bf16*)d_ws;
  bf16* A2 = A1 + (size_t)Bdim * Ktot;
  bf16* Wf = A2 + (size_t)Bdim * Ktot;
  bf16* Wn = Wf + (size_t)Hdim * Ktot;
  // total ws use: 4 * 16.78 MB = 67.1 MB

  const int n8w = Hdim * Ktot / 8;
  cvt_kernel<<<1024, 256, 0, stream>>>(w_f, Wf, n8w);
  cvt_kernel<<<1024, 256, 0, stream>>>(w_n, Wn, n8w);
  build_a_kernel<<<1024, 256, 0, stream>>>(hx, x, A1, A2);

  // GEMM1: fg path. fg (fp32) staged in d_out; bf16(fg*hx) -> A2 left half.
  gemm_kernel<0><<<256, 512, 0, stream>>>(A1, Wf, b_f, hx, out, A2, nullptr);
  // GEMM2: ng path + final hy into d_out (reads fg from d_out, fg*hx from A2).
  gemm_kernel<1><<<256, 512, 0, stream>>>(A2, Wn, b_n, nullptr, out, A2, out);
}

// Round 7
// 115.851 us; speedup vs baseline: 1.0429x; 1.0174x over previous
//
#include <hip/hip_runtime.h>
#include <stdint.h>

// FSUMGUCell: hy = (1-fg)*ng + fg*hx
//   fg = ( [hx|x]@w_f^T + b_f + 1 ) * 0.5
//   ng =   [fg*hx|x]@w_n^T + b_n
// B=H=I=2048, K=H+I=4096. bf16 MFMA path.
//
// Round 7: keep the verified round-6 GEMM core (split-K x2, staggered windows,
// 50 us/GEMM = LDS-port-bound floor for 128^2 tiles at this grid). Cut the
// off-GEMM traffic instead:
//  - one fused prep kernel (cvt Wf, cvt Wn, build A1) — 2 fewer launches
//  - A2 right half eliminated: GEMM2's group 1 (K in [2048,4096)) stages
//    directly from A1's right half (identical data)
//  - fg fp32 (16MB wr + 16 rd) -> omf = (1-fg) bf16 (8 wr + 8 rd)
// WS: A1 16MB | A2L 8MB | Wf 16MB | Wn 16MB | omf 8MB = 64 MB.

#define Hdim 2048
#define Idim 2048
#define Bdim 2048
#define Ktot 4096
#define KHALF 2048
#define NSTEP (KHALF / 64)

typedef __bf16 bf16;
typedef __bf16 bf16x8 __attribute__((ext_vector_type(8)));
typedef float  f32x4  __attribute__((ext_vector_type(4)));

__device__ __forceinline__ void gload_lds16(const bf16* g, bf16* l) {
  __builtin_amdgcn_global_load_lds(
      (const __attribute__((address_space(1))) unsigned int*)g,
      (__attribute__((address_space(3))) unsigned int*)l,
      16, 0, 0);
}

// ---- fused prep: Wf cvt | Wn cvt | A1 = [hx|x] cvt (all f32 -> bf16 x8) ----
__global__ void prep_kernel(const float* __restrict__ w_f, const float* __restrict__ w_n,
                            const float* __restrict__ hx, const float* __restrict__ x,
                            bf16* __restrict__ Wf, bf16* __restrict__ Wn,
                            bf16* __restrict__ A1) {
  const int n8 = Hdim * Ktot / 8;           // 1,048,576 chunks per segment
  int stride = gridDim.x * blockDim.x;
  for (int i = blockIdx.x * blockDim.x + threadIdx.x; i < 3 * n8; i += stride) {
    const float* src;
    bf16* dst;
    if (i < n8) {
      src = w_f + (size_t)i * 8;  dst = Wf + (size_t)i * 8;
    } else if (i < 2 * n8) {
      int j = i - n8;
      src = w_n + (size_t)j * 8;  dst = Wn + (size_t)j * 8;
    } else {
      int j = i - 2 * n8;
      int e = j * 8;
      int b = e >> 12;                      // / 4096
      int k = e & (Ktot - 1);
      src = (k < Hdim) ? (hx + (size_t)b * Hdim + k)
                       : (x  + (size_t)b * Idim + (k - Hdim));
      dst = A1 + (size_t)e;
    }
    const float4* s = (const float4*)src;
    float4 va = s[0], vb = s[1];
    bf16x8 o;
    o[0]=(bf16)va.x; o[1]=(bf16)va.y; o[2]=(bf16)va.z; o[3]=(bf16)va.w;
    o[4]=(bf16)vb.x; o[5]=(bf16)vb.y; o[6]=(bf16)vb.z; o[7]=(bf16)vb.w;
    *((bf16x8*)dst) = o;
  }
}

// ---- 128x128 GEMM, split-K in-block, 8 waves, staggered windows ----
// C[row][col] = sum_k Asrc[row][k] * W[col][k], W [2048][4096] bf16 (B^T).
// EPI0: Asrc = A1 [2048][4096]. EPI1: group 0 reads A2L [2048][2048]
// (= bf16(fg*hx)), group 1 reads A1 right half (= x) — per-group uniform.
// Per group: LDS tiles [128][64] bf16 x2 bufs; 16B-chunk XOR swizzle
// (LDS[row][c] holds global chunk c ^ (row&7); staged via inverse-swizzled
// global source since global_load_lds writes linearly; read applies same XOR).
template<int EPI>
__global__ __launch_bounds__(512)
void gemm_kernel(const bf16* __restrict__ A1, const bf16* __restrict__ A2L,
                 const bf16* __restrict__ W,
                 const float* __restrict__ bias,
                 const float* __restrict__ hx,   // EPI0 only
                 bf16* __restrict__ OMF,         // EPI0: write (1-fg) ; EPI1: read
                 bf16* __restrict__ A2Lw,        // EPI0: write bf16(fg*hx)
                 float* __restrict__ OUT)        // EPI1: write hy
{
  __shared__ bf16 lds[2][2][2][8192];   // [group][buf][A=0/B=1][128*64] = 128 KB

  int bid  = blockIdx.x;
  int sbid = (bid & 7) * 32 + (bid >> 3);   // XCD swizzle (256%8==0, bijective)
  int tm = sbid >> 4, tn = sbid & 15;

  int tid  = threadIdx.x;
  int w = tid >> 6, lane = tid & 63;
  int g = w >> 2, sub = w & 3;
  int wrow = (sub >> 1) * 64;   // 2x2 wave grid within tile: 64x64 per wave
  int wcol = (sub & 1) * 64;
  int fr = lane & 15, fq = lane >> 4;
  int swz = fr & 7;

  // staging: per group-step 2048 16B chunks (A 1024 + B 1024), 256 threads ->
  // 8 loads/thread. Thread gtid, pass jj: row = jj*32 + (gtid>>3), dest chunk
  // gtid&7, source chunk (gtid&7)^(row&7) (inverse swizzle).
  int gtid = sub * 64 + lane;
  int srow = gtid >> 3;
  int csrc = (gtid & 7) ^ (srow & 7);

  const bf16* pA;
  size_t strA;
  if (EPI == 0) {
    pA = A1 + (size_t)(tm * 128 + srow) * Ktot + csrc * 8 + g * KHALF;
    strA = Ktot;
  } else if (g == 0) {
    pA = A2L + (size_t)(tm * 128 + srow) * KHALF + csrc * 8;   // fg*hx, K 0..2047
    strA = KHALF;
  } else {
    pA = A1 + (size_t)(tm * 128 + srow) * Ktot + csrc * 8 + Hdim; // x, K 2048..4095
    strA = Ktot;
  }
  const bf16* pB = W + (size_t)(tn * 128 + srow) * Ktot + csrc * 8 + g * KHALF;
  int lbase = sub * 512;                     // + jj*2048 ; gload adds lane*16B

#define STAGE(buf, koff) do {                                                      \
    _Pragma("unroll")                                                              \
    for (int jj = 0; jj < 4; ++jj) {                                               \
      gload_lds16(pA + (size_t)jj * 32 * strA + (koff), &lds[g][buf][0][jj * 2048 + lbase]); \
      gload_lds16(pB + (size_t)jj * 32 * Ktot + (koff), &lds[g][buf][1][jj * 2048 + lbase]); \
    }                                                                              \
  } while (0)

#define READS(buf_, j_) do {                                                       \
    int ch = (((j_) * 4 + fq) ^ swz) * 8;                                          \
    _Pragma("unroll")                                                              \
    for (int m = 0; m < 4; ++m)                                                    \
      af[m] = *(const bf16x8*)&lds[g][buf_][0][(wrow + m * 16 + fr) * 64 + ch];    \
    _Pragma("unroll")                                                              \
    for (int n = 0; n < 4; ++n)                                                    \
      bv[n] = *(const bf16x8*)&lds[g][buf_][1][(wcol + n * 16 + fr) * 64 + ch];    \
  } while (0)

  f32x4 acc[4][4] = {};

  STAGE(0, 0);                          // prologue: tile 0 -> buf 0

  const int NW = 2 * NSTEP + 1;         // 65 windows; g1 trails by 1
  for (int win = 0; win < NW; ++win) {
    int w2 = win - g;
    bool active = (unsigned)w2 < (unsigned)(2 * NSTEP);
    int t = w2 >> 1, j = w2 & 1, buf = t & 1;
    bf16x8 af[4], bv[4];
    if (active) {
      if (j == 1) READS(buf, 1);        // tile complete since last window: safe
      else asm volatile("s_waitcnt vmcnt(0)" ::: "memory");  // own stage loads done
    }
    __builtin_amdgcn_s_barrier();       // group-wide: stage(t) fully landed
    if (active) {
      if (j == 0) {
        READS(buf, 0);                  // after barrier (publishes stage(t))
        if (t + 1 < NSTEP) STAGE(buf ^ 1, (t + 1) * 64);
      }
      __builtin_amdgcn_s_setprio(1);
      #pragma unroll
      for (int m = 0; m < 4; ++m)
        #pragma unroll
        for (int n = 0; n < 4; ++n)
          acc[m][n] = __builtin_amdgcn_mfma_f32_16x16x32_bf16(af[m], bv[n], acc[m][n], 0, 0, 0);
      __builtin_amdgcn_s_setprio(0);
    }
  }
#undef STAGE
#undef READS

  // ---- cross-group reduction via LDS (reuse tile space), fused epilogue ----
  __syncthreads();
  float* xch = (float*)&lds[0][0][0][0];    // 4 subs x 16 KB = 64 KB
  if (g == 1) {
    #pragma unroll
    for (int m = 0; m < 4; ++m)
      #pragma unroll
      for (int n = 0; n < 4; ++n)
        *(f32x4*)&xch[sub * 4096 + (m * 4 + n) * 256 + lane * 4] = acc[m][n];
  }
  __syncthreads();
  if (g == 0) {
    // C/D layout: col = lane&15, row = (lane>>4)*4 + i  [m89 verified]
    int row0 = tm * 128 + wrow + fq * 4;
    int col0 = tn * 128 + wcol + fr;
    #pragma unroll
    for (int n = 0; n < 4; ++n) {
      int gcol = col0 + n * 16;
      float bv = bias[gcol];
      #pragma unroll
      for (int m = 0; m < 4; ++m) {
        f32x4 part = *(const f32x4*)&xch[sub * 4096 + (m * 4 + n) * 256 + lane * 4];
        #pragma unroll
        for (int i = 0; i < 4; ++i) {
          int grow = row0 + m * 16 + i;
          size_t idx = (size_t)grow * Hdim + gcol;
          float v = acc[m][n][i] + part[i] + bv;
          if (EPI == 0) {
            float fg   = (v + 1.0f) * 0.5f;
            float fghx = fg * hx[idx];
            OMF[idx]  = (bf16)(1.0f - fg);                  // (1-fg) bf16
            A2Lw[(size_t)grow * KHALF + gcol] = (bf16)fghx; // GEMM2 A left half
          } else {
            float omf  = (float)OMF[idx];                   // 1-fg (bf16)
            float fghx = (float)A2L[idx];                   // bf16(fg*hx)
            OUT[idx] = omf * v + fghx;                      // (1-fg)*ng + fg*hx
          }
        }
      }
    }
  }
}

extern "C" void kernel_launch(void* const* d_in, const int* in_sizes, int n_in,
                              void* d_out, int out_size, void* d_ws, size_t ws_size,
                              hipStream_t stream) {
  const float* x   = (const float*)d_in[0];
  const float* hx  = (const float*)d_in[1];
  const float* w_f = (const float*)d_in[2];
  const float* b_f = (const float*)d_in[3];
  const float* w_n = (const float*)d_in[4];
  const float* b_n = (const float*)d_in[5];
  float* out = (float*)d_out;

  bf16* A1  = (bf16*)d_ws;                       // [2048][4096] = 16 MB
  bf16* A2L = A1  + (size_t)Bdim * Ktot;         // [2048][2048] =  8 MB
  bf16* Wf  = A2L + (size_t)Bdim * KHALF;        // [2048][4096] = 16 MB
  bf16* Wn  = Wf  + (size_t)Hdim * Ktot;         // [2048][4096] = 16 MB
  bf16* OMF = Wn  + (size_t)Hdim * Ktot;         // [2048][2048] =  8 MB
  // total 64 MB

  prep_kernel<<<2048, 256, 0, stream>>>(w_f, w_n, hx, x, Wf, Wn, A1);

  // GEMM1: fg path -> omf (1-fg, bf16) + A2L (bf16 fg*hx).
  gemm_kernel<0><<<256, 512, 0, stream>>>(A1, nullptr, Wf, b_f, hx, OMF, A2L, nullptr);
  // GEMM2: ng path; A = [A2L | A1 right half]; hy -> d_out.
  gemm_kernel<1><<<256, 512, 0, stream>>>(A1, A2L, Wn, b_n, nullptr, OMF, nullptr, out);
}